// Round 3
// baseline (1616.020 us; speedup 1.0000x reference)
//
#include <hip/hip_runtime.h>
#include <hip/hip_fp16.h>

#define HD 128
#define BM 128

typedef _Float16 f16x8 __attribute__((ext_vector_type(8)));
typedef float f32x4 __attribute__((ext_vector_type(4)));

// ---- d_ws layout ----
// bytes 0..511    : float sums[128]
// bytes 512..1023 : float sumsq[128]
// bytes 1024..1535: float scale[128]
// bytes 1536..2047: float shift[128]
// bytes 4096..    : packed fp16 weights (fragment-ordered), hi/lo split
#define W11H_OFF 0
#define W11L_OFF 49152
#define W12H_OFF 98304
#define W12L_OFF 114688
#define W13H_OFF 131072
#define W13L_OFF 147456

__device__ __forceinline__ float gelu_exact(float x) {
  return 0.5f * x * (1.0f + erff(x * 0.70710678118654752f));
}

// Repack W11 (384x128), W12, W13 (128x128) into MFMA B-fragment order:
// frag (ks, fc): element (lane, i) = W[ks*32 + (lane>>4)*8 + i][fc*16 + (lane&15)]
// stored at frag*512 + lane*8 + i, separately for hi (fp16(w)) and lo (fp16(w-hi)).
__global__ __launch_bounds__(256) void repack_w(
    const float* __restrict__ W11, const float* __restrict__ W12,
    const float* __restrict__ W13, _Float16* __restrict__ wp)
{
  int t = blockIdx.x * 256 + threadIdx.x;   // 0..10239
  const float* W; int local, hb, lb;
  if (t < 6144)      { W = W11; local = t;        hb = W11H_OFF; lb = W11L_OFF; }
  else if (t < 8192) { W = W12; local = t - 6144; hb = W12H_OFF; lb = W12L_OFF; }
  else               { W = W13; local = t - 8192; hb = W13H_OFF; lb = W13L_OFF; }
  int frag = local >> 6, lane = local & 63;
  int k0  = (frag >> 3) * 32 + ((lane >> 4) * 8);
  int col = (frag & 7) * 16 + (lane & 15);
  _Float16* Hp = wp + hb + (size_t)local * 8;
  _Float16* Lp = wp + lb + (size_t)local * 8;
#pragma unroll
  for (int i = 0; i < 8; ++i) {
    float w = W[(size_t)(k0 + i) * HD + col];
    _Float16 h = (_Float16)w;
    Hp[i] = h;
    Lp[i] = (_Float16)(w - (float)h);
  }
}

// Fused: gather-concat -> gelu(xW11+b11) -> gelu(hW12+b12) -> hW13+b13 + ea = x
// Writes x to xout, accumulates per-column sum/sumsq into stats[0..255].
// Barrier-free: each wave owns 32 edges; h tile lives in the wave's private LDS.
__global__ __launch_bounds__(256, 2) void fused_mlp(
    const float* __restrict__ src_na, const float* __restrict__ dst_na,
    const float* __restrict__ ea, const int* __restrict__ eidx,
    const float* __restrict__ b11, const float* __restrict__ b12,
    const float* __restrict__ b13, const _Float16* __restrict__ wp,
    float* __restrict__ stats, float* __restrict__ xout, int E)
{
  __shared__ unsigned int hsm[4 * 32 * HD];   // 64 KiB: per-wave 32x128 packed (hi16|lo16)
  const int tid  = threadIdx.x;
  const int lane = tid & 63;
  const int wave = tid >> 6;
  const int l15  = lane & 15;
  const int lg   = lane >> 4;
  const int e0   = blockIdx.x * BM + wave * 32;
  unsigned int* myh = hsm + wave * 32 * HD;

  int erow[2], sidx[2], didx[2];
#pragma unroll
  for (int m = 0; m < 2; ++m) {
    int e = e0 + m * 16 + l15;
    e = e < E ? e : E - 1;
    erow[m] = e;
    didx[m] = eidx[e];       // edge_idx[0] = dst
    sidx[m] = eidx[E + e];   // edge_idx[1] = src
  }

  const f32x4 vzero = {0.f, 0.f, 0.f, 0.f};
  f32x4 acc[2][8];
#pragma unroll
  for (int m = 0; m < 2; ++m)
#pragma unroll
    for (int f = 0; f < 8; ++f) acc[m][f] = vzero;

  // ---------------- Layer 1: K = 384 (src | ea | dst) ----------------
  const _Float16* w11h = wp + W11H_OFF;
  const _Float16* w11l = wp + W11L_OFF;
#pragma unroll 2
  for (int ks = 0; ks < 12; ++ks) {
    const int part = ks >> 2;
    const int kc = (ks & 3) * 32 + lg * 8;
    f16x8 ah[2], al[2];
#pragma unroll
    for (int m = 0; m < 2; ++m) {
      const float* rp;
      if (part == 0)      rp = src_na + (size_t)sidx[m] * HD;
      else if (part == 1) rp = ea + (size_t)erow[m] * HD;
      else                rp = dst_na + (size_t)didx[m] * HD;
      float4 v0 = *(const float4*)(rp + kc);
      float4 v1 = *(const float4*)(rp + kc + 4);
      float v[8] = {v0.x, v0.y, v0.z, v0.w, v1.x, v1.y, v1.z, v1.w};
#pragma unroll
      for (int i = 0; i < 8; ++i) {
        _Float16 hh = (_Float16)v[i];
        ah[m][i] = hh;
        al[m][i] = (_Float16)(v[i] - (float)hh);
      }
    }
    const _Float16* bhp = w11h + (size_t)(ks * 8) * 512 + lane * 8;
    const _Float16* blp = w11l + (size_t)(ks * 8) * 512 + lane * 8;
#pragma unroll
    for (int fc = 0; fc < 8; ++fc) {
      f16x8 bh = *(const f16x8*)(bhp + fc * 512);
      f16x8 bl = *(const f16x8*)(blp + fc * 512);
#pragma unroll
      for (int m = 0; m < 2; ++m) {
        acc[m][fc] = __builtin_amdgcn_mfma_f32_16x16x32_f16(ah[m], bh, acc[m][fc], 0, 0, 0);
        acc[m][fc] = __builtin_amdgcn_mfma_f32_16x16x32_f16(ah[m], bl, acc[m][fc], 0, 0, 0);
        acc[m][fc] = __builtin_amdgcn_mfma_f32_16x16x32_f16(al[m], bh, acc[m][fc], 0, 0, 0);
      }
    }
  }

  // store h = gelu(acc + bias) into LDS as (hi16|lo16), XOR-swizzled
  auto store_h = [&](const float* __restrict__ bias) {
#pragma unroll
    for (int fc = 0; fc < 8; ++fc) {
      int col = fc * 16 + l15;
      float b = bias[col];
#pragma unroll
      for (int m = 0; m < 2; ++m)
#pragma unroll
        for (int r = 0; r < 4; ++r) {
          int row = m * 16 + lg * 4 + r;
          float hv = gelu_exact(acc[m][fc][r] + b);
          _Float16 hh = (_Float16)hv;
          _Float16 hl = (_Float16)(hv - (float)hh);
          unsigned int u = ((unsigned int)__builtin_bit_cast(unsigned short, hh) << 16)
                         | (unsigned int)__builtin_bit_cast(unsigned short, hl);
          unsigned int off = (unsigned int)(row * HD + col) * 4u;
          off ^= ((unsigned int)(row & 7)) << 4;
          *(unsigned int*)((char*)myh + off) = u;
        }
    }
  };

  // one 128x128 layer from the LDS h tile
  auto mlp_layer = [&](const _Float16* __restrict__ wh, const _Float16* __restrict__ wl) {
#pragma unroll
    for (int m = 0; m < 2; ++m)
#pragma unroll
      for (int f = 0; f < 8; ++f) acc[m][f] = vzero;
#pragma unroll
    for (int ks = 0; ks < 4; ++ks) {
      f16x8 ah[2], al[2];
#pragma unroll
      for (int m = 0; m < 2; ++m) {
        int row = m * 16 + l15;
        unsigned int base = (unsigned int)(row * HD + ks * 32 + lg * 8) * 4u;
        unsigned int sz = ((unsigned int)(row & 7)) << 4;
        uint4 q0 = *(const uint4*)((const char*)myh + (base ^ sz));
        uint4 q1 = *(const uint4*)((const char*)myh + ((base + 16) ^ sz));
        unsigned int uu[8] = {q0.x, q0.y, q0.z, q0.w, q1.x, q1.y, q1.z, q1.w};
#pragma unroll
        for (int i = 0; i < 8; ++i) {
          ah[m][i] = __builtin_bit_cast(_Float16, (unsigned short)(uu[i] >> 16));
          al[m][i] = __builtin_bit_cast(_Float16, (unsigned short)(uu[i] & 0xffffu));
        }
      }
      const _Float16* bhp = wh + (size_t)(ks * 8) * 512 + lane * 8;
      const _Float16* blp = wl + (size_t)(ks * 8) * 512 + lane * 8;
#pragma unroll
      for (int fc = 0; fc < 8; ++fc) {
        f16x8 bh = *(const f16x8*)(bhp + fc * 512);
        f16x8 bl = *(const f16x8*)(blp + fc * 512);
#pragma unroll
        for (int m = 0; m < 2; ++m) {
          acc[m][fc] = __builtin_amdgcn_mfma_f32_16x16x32_f16(ah[m], bh, acc[m][fc], 0, 0, 0);
          acc[m][fc] = __builtin_amdgcn_mfma_f32_16x16x32_f16(ah[m], bl, acc[m][fc], 0, 0, 0);
          acc[m][fc] = __builtin_amdgcn_mfma_f32_16x16x32_f16(al[m], bh, acc[m][fc], 0, 0, 0);
        }
      }
    }
  };

  store_h(b11);
  mlp_layer(wp + W12H_OFF, wp + W12L_OFF);
  store_h(b12);
  mlp_layer(wp + W13H_OFF, wp + W13L_OFF);

  // ---------------- Epilogue: x = acc + b13 + ea; write; column stats ----------------
#pragma unroll
  for (int fc = 0; fc < 8; ++fc) {
    int col = fc * 16 + l15;
    float b = b13[col];
    float s = 0.f, sq = 0.f;
#pragma unroll
    for (int m = 0; m < 2; ++m)
#pragma unroll
      for (int r = 0; r < 4; ++r) {
        int row = m * 16 + lg * 4 + r;
        int e = e0 + row;
        bool valid = e < E;          // guard: clamped tail rows must not
        e = valid ? e : E - 1;       // contribute to BN statistics
        float x = acc[m][fc][r] + b + ea[(size_t)e * HD + col];
        xout[(size_t)e * HD + col] = x;
        float xv = valid ? x : 0.f;
        s += xv; sq += xv * xv;
      }
    s  += __shfl_xor(s, 16);  s  += __shfl_xor(s, 32);
    sq += __shfl_xor(sq, 16); sq += __shfl_xor(sq, 32);
    if (lg == 0) {
      atomicAdd(&stats[col], s);
      atomicAdd(&stats[HD + col], sq);
    }
  }
}

__global__ void bn_finalize(float* __restrict__ stats, const float* __restrict__ gamma,
                            const float* __restrict__ beta, float invE)
{
  int c = threadIdx.x;
  if (c < HD) {
    float mean = stats[c] * invE;
    float var  = stats[HD + c] * invE - mean * mean;
    float sc   = gamma[c] * rsqrtf(var + 1e-5f);
    stats[2 * HD + c] = sc;
    stats[3 * HD + c] = beta[c] - mean * sc;
  }
}

__global__ __launch_bounds__(256) void bn_apply(float* __restrict__ x,
                                                const float* __restrict__ stats,
                                                long long n4)
{
  __shared__ float4 s_sc[32], s_sh[32];
  if (threadIdx.x < 32) {
    s_sc[threadIdx.x] = ((const float4*)(stats + 2 * HD))[threadIdx.x];
    s_sh[threadIdx.x] = ((const float4*)(stats + 3 * HD))[threadIdx.x];
  }
  __syncthreads();
  long long i = (long long)blockIdx.x * 256 + threadIdx.x;
  const long long stride = (long long)gridDim.x * 256;
  float4* __restrict__ x4 = (float4*)x;
  for (; i < n4; i += stride) {
    float4 v = x4[i];
    int c4 = (int)(i & 31);
    float4 a = s_sc[c4], b = s_sh[c4];
    v.x = v.x * a.x + b.x;
    v.y = v.y * a.y + b.y;
    v.z = v.z * a.z + b.z;
    v.w = v.w * a.w + b.w;
    x4[i] = v;
  }
}

extern "C" void kernel_launch(void* const* d_in, const int* in_sizes, int n_in,
                              void* d_out, int out_size, void* d_ws, size_t ws_size,
                              hipStream_t stream) {
  const float* src_na = (const float*)d_in[0];
  const float* dst_na = (const float*)d_in[1];
  const float* ea     = (const float*)d_in[2];
  const int*   eidx   = (const int*)d_in[3];
  const float* W11    = (const float*)d_in[4];
  const float* b11    = (const float*)d_in[5];
  const float* W12    = (const float*)d_in[6];
  const float* b12    = (const float*)d_in[7];
  const float* W13    = (const float*)d_in[8];
  const float* b13    = (const float*)d_in[9];
  const float* gamma  = (const float*)d_in[10];
  const float* beta   = (const float*)d_in[11];
  const int E = in_sizes[3] / 2;

  float*    stats = (float*)d_ws;
  _Float16* wp    = (_Float16*)((char*)d_ws + 4096);
  float*    xout  = (float*)d_out;

  hipMemsetAsync(d_ws, 0, 1024, stream);                 // zero sums/sumsq
  repack_w<<<40, 256, 0, stream>>>(W11, W12, W13, wp);
  fused_mlp<<<(E + BM - 1) / BM, 256, 0, stream>>>(src_na, dst_na, ea, eidx,
                                                   b11, b12, b13, wp, stats, xout, E);
  bn_finalize<<<1, 128, 0, stream>>>(stats, gamma, beta, 1.0f / (float)E);
  long long n4 = (long long)E * HD / 4;
  bn_apply<<<4096, 256, 0, stream>>>(xout, stats, n4);
}